// Round 2
// baseline (346.148 us; speedup 1.0000x reference)
//
#include <hip/hip_runtime.h>
#include <hip/hip_bf16.h>

// Problem constants
#define HEADS   12
#define HD      64
#define NTOK    197          // N_PATCH + 1
#define BATCH   64
#define M_TOK   (BATCH*NTOK) // 12608
#define DIMC    768
#define NPAIR   (NTOK*NTOK)  // 38809
#define MPAD    224          // key/m dimension padded to 7*32

typedef __attribute__((ext_vector_type(8))) short bf16x8;  // 8 bf16 (4 VGPRs)
typedef __attribute__((ext_vector_type(4))) short s16x4;
typedef __attribute__((ext_vector_type(4))) float f32x4;

// fp32 -> bf16 round-to-nearest-even (bit manipulation; no NaN in valid paths)
static __device__ __forceinline__ short f2bf(float f) {
    unsigned u = __float_as_uint(f);
    unsigned r = (u + 0x7FFFu + ((u >> 16) & 1u)) >> 16;
    return (short)r;
}

// ---------------------------------------------------------------------------
// Kernel 0: expand rpb_table via rel_pos_index -> rpb_full[h][n*197+m]
// ---------------------------------------------------------------------------
__global__ void rpb_kernel(const float* __restrict__ table,
                           const int* __restrict__ idx,
                           float* __restrict__ rpb_full) {
    int i = blockIdx.x * 256 + threadIdx.x;
    if (i >= NPAIR) return;
    int id = idx[i];
    #pragma unroll
    for (int h = 0; h < HEADS; ++h)
        rpb_full[(size_t)h * NPAIR + i] = table[id * HEADS + h];
}

// ---------------------------------------------------------------------------
// Kernel 1: QKV GEMM  (x[12608,768] @ qkv_w[2304,768]^T + bias), epilogue
// scatters q (scaled, bf16), k (bf16), v^T (bf16, m-padded to 224).
// 128x128 tile, BK=64, 4 waves of 64x64, swizzled LDS, 16x16x32 bf16 MFMA.
// ---------------------------------------------------------------------------
__global__ __launch_bounds__(256) void qkv_gemm_kernel(
    const float* __restrict__ x, const float* __restrict__ w,
    const float* __restrict__ qb, const float* __restrict__ vb,
    short* __restrict__ q_ws, short* __restrict__ k_ws,
    short* __restrict__ vt_ws) {
    __shared__ __align__(16) short lds_a[128 * 64];
    __shared__ __align__(16) short lds_b[128 * 64];
    const int tid  = threadIdx.x;
    const int lane = tid & 63;
    const int wv   = tid >> 6;           // 0..3
    const int wr   = wv >> 1, wc = wv & 1;
    const int bm   = blockIdx.y, bn = blockIdx.x;
    const int g    = lane >> 4, c16 = lane & 15;

    f32x4 acc[4][4] = {};
    const int srow = tid >> 4;   // 0..15
    const int sc4  = tid & 15;   // float4 column

    for (int kt = 0; kt < 12; ++kt) {
        // stage A: x rows (tokens)
        #pragma unroll
        for (int r8 = 0; r8 < 8; ++r8) {
            int row = srow + r8 * 16;
            int gr  = bm * 128 + row; if (gr > M_TOK - 1) gr = M_TOK - 1;
            const float4 v = *(const float4*)(x + (size_t)gr * DIMC + kt * 64 + sc4 * 4);
            s16x4 bv; bv[0] = f2bf(v.x); bv[1] = f2bf(v.y); bv[2] = f2bf(v.z); bv[3] = f2bf(v.w);
            *(s16x4*)&lds_a[row * 64 + ((sc4 * 4) ^ ((row & 7) << 3))] = bv;
        }
        // stage B: qkv_w rows (output columns), k-contiguous
        #pragma unroll
        for (int r8 = 0; r8 < 8; ++r8) {
            int row = srow + r8 * 16;
            int gc  = bn * 128 + row;
            const float4 v = *(const float4*)(w + (size_t)gc * DIMC + kt * 64 + sc4 * 4);
            s16x4 bv; bv[0] = f2bf(v.x); bv[1] = f2bf(v.y); bv[2] = f2bf(v.z); bv[3] = f2bf(v.w);
            *(s16x4*)&lds_b[row * 64 + ((sc4 * 4) ^ ((row & 7) << 3))] = bv;
        }
        __syncthreads();
        #pragma unroll
        for (int ks = 0; ks < 2; ++ks) {
            bf16x8 af[4], bfr[4];
            const int kk = ks * 32 + (g << 3);
            #pragma unroll
            for (int i = 0; i < 4; ++i) {
                int row = wr * 64 + i * 16 + c16;
                af[i] = *(const bf16x8*)&lds_a[row * 64 + (kk ^ ((row & 7) << 3))];
            }
            #pragma unroll
            for (int j = 0; j < 4; ++j) {
                int row = wc * 64 + j * 16 + c16;
                bfr[j] = *(const bf16x8*)&lds_b[row * 64 + (kk ^ ((row & 7) << 3))];
            }
            #pragma unroll
            for (int i = 0; i < 4; ++i)
                #pragma unroll
                for (int j = 0; j < 4; ++j)
                    acc[i][j] = __builtin_amdgcn_mfma_f32_16x16x32_bf16(af[i], bfr[j], acc[i][j], 0, 0, 0);
        }
        __syncthreads();
    }

    // epilogue: C/D layout col = lane&15, row = (lane>>4)*4 + reg  [m89-verified]
    #pragma unroll
    for (int i = 0; i < 4; ++i) {
        const int tbase = bm * 128 + wr * 64 + i * 16 + (g << 2);
        #pragma unroll
        for (int j = 0; j < 4; ++j) {
            const int c     = bn * 128 + wc * 64 + j * 16 + c16;
            const int which = c / DIMC;            // 0=q 1=k 2=v
            const int r     = c - which * DIMC;
            const int h     = r >> 6, d = r & 63;
            #pragma unroll
            for (int rg = 0; rg < 4; ++rg) {
                const int tt = tbase + rg;
                if (tt >= M_TOK) continue;
                const int b = tt / NTOK, n = tt - b * NTOK;
                const size_t bh = (size_t)b * HEADS + h;
                float val = acc[i][j][rg];
                if (which == 0) {
                    val = (val + qb[r]) * 0.125f;                    // q scale hd^-0.5
                    q_ws[(bh * NTOK + n) * HD + d] = f2bf(val);
                } else if (which == 1) {
                    k_ws[(bh * NTOK + n) * HD + d] = f2bf(val);
                } else {
                    val += vb[r];
                    vt_ws[(bh * HD + d) * MPAD + n] = f2bf(val);     // transposed for PV B-frags
                }
            }
        }
    }
}

// ---------------------------------------------------------------------------
// Kernel 2: attention. 1 wave per (b,h, 16-row tile). Q/K/V fragments read
// straight from global (L2-resident per (b,h)); only P staged in LDS.
// ---------------------------------------------------------------------------
__global__ __launch_bounds__(64) void attn_kernel(
    const short* __restrict__ q_ws, const short* __restrict__ k_ws,
    const short* __restrict__ vt_ws, const float* __restrict__ rpb_full,
    short* __restrict__ o_ws) {
    __shared__ __align__(16) short p_lds[16 * 232];   // rows padded to 232 (2-way banks)
    const int lane = threadIdx.x;
    const int rt   = blockIdx.x;                      // 0..12 row tile
    const int bh   = blockIdx.y;                      // 0..767
    const int b    = bh / HEADS, h = bh - b * HEADS;
    const int g    = lane >> 4, c16 = lane & 15;

    // Q fragments (A-operand): row n = rt*16 + c16, k-contiguous in d
    bf16x8 qa0, qa1;
    {
        const size_t base = ((size_t)bh * NTOK + (rt * 16 + c16)) * HD + g * 8;
        qa0 = *(const bf16x8*)(q_ws + base);
        qa1 = *(const bf16x8*)(q_ws + base + 32);
    }

    // S = Q K^T over 14 column tiles (m padded to 224; pads masked later)
    f32x4 sacc[14];
    #pragma unroll
    for (int t = 0; t < 14; ++t) sacc[t] = (f32x4){0.f, 0.f, 0.f, 0.f};
    #pragma unroll
    for (int mt = 0; mt < 14; ++mt) {
        const size_t base = ((size_t)bh * NTOK + (mt * 16 + c16)) * HD + g * 8;
        bf16x8 kb0 = *(const bf16x8*)(k_ws + base);
        bf16x8 kb1 = *(const bf16x8*)(k_ws + base + 32);
        sacc[mt] = __builtin_amdgcn_mfma_f32_16x16x32_bf16(qa0, kb0, sacc[mt], 0, 0, 0);
        sacc[mt] = __builtin_amdgcn_mfma_f32_16x16x32_bf16(qa1, kb1, sacc[mt], 0, 0, 0);
    }

    // + rpb, mask m>=197, row max (rows live in 16-lane groups: row=(g*4+rg))
    float mx[4] = {-1e30f, -1e30f, -1e30f, -1e30f};
    #pragma unroll
    for (int rg = 0; rg < 4; ++rg) {
        const int n = rt * 16 + g * 4 + rg;
        #pragma unroll
        for (int mt = 0; mt < 14; ++mt) {
            const int m = mt * 16 + c16;
            float s = sacc[mt][rg];
            if (n < NTOK && m < NTOK) s += rpb_full[(size_t)h * NPAIR + n * NTOK + m];
            else                      s = -1e30f;
            sacc[mt][rg] = s;
            mx[rg] = fmaxf(mx[rg], s);
        }
    }
    #pragma unroll
    for (int off = 1; off < 16; off <<= 1)
        #pragma unroll
        for (int rg = 0; rg < 4; ++rg)
            mx[rg] = fmaxf(mx[rg], __shfl_xor(mx[rg], off, 64));

    // P = exp(S - max), row sums, stage P (bf16) to LDS in A-fragment layout
    float sm[4] = {0.f, 0.f, 0.f, 0.f};
    #pragma unroll
    for (int mt = 0; mt < 14; ++mt)
        #pragma unroll
        for (int rg = 0; rg < 4; ++rg) {
            float p = exp2f((sacc[mt][rg] - mx[rg]) * 1.44269504f);
            sm[rg] += p;
            p_lds[(g * 4 + rg) * 232 + mt * 16 + c16] = f2bf(p);
        }
    #pragma unroll
    for (int off = 1; off < 16; off <<= 1)
        #pragma unroll
        for (int rg = 0; rg < 4; ++rg)
            sm[rg] += __shfl_xor(sm[rg], off, 64);
    __syncthreads();   // single wave: compiles to a waitcnt

    // O = P @ V : A = P from LDS, B = V from global v^T (k-contiguous in m)
    f32x4 oacc[4] = {};
    #pragma unroll
    for (int ks = 0; ks < 7; ++ks) {
        const int kk = ks * 32 + g * 8;
        bf16x8 pa = *(const bf16x8*)&p_lds[c16 * 232 + kk];
        #pragma unroll
        for (int j = 0; j < 4; ++j) {
            const int d = j * 16 + c16;
            bf16x8 vbf = *(const bf16x8*)(vt_ws + ((size_t)bh * HD + d) * MPAD + kk);
            oacc[j] = __builtin_amdgcn_mfma_f32_16x16x32_bf16(pa, vbf, oacc[j], 0, 0, 0);
        }
    }

    // normalize + store o_ws[t][h*64+d] (bf16, row-major tokens x 768)
    #pragma unroll
    for (int rg = 0; rg < 4; ++rg) {
        const int n = rt * 16 + g * 4 + rg;
        if (n >= NTOK) continue;
        const float inv = 1.0f / sm[rg];
        #pragma unroll
        for (int j = 0; j < 4; ++j)
            o_ws[((size_t)(b * NTOK + n)) * DIMC + h * HD + j * 16 + c16] =
                f2bf(oacc[j][rg] * inv);
    }
}

// ---------------------------------------------------------------------------
// Kernel 3: proj GEMM  (o[12608,768] @ proj_w[768,768]^T + proj_b) -> fp32 out
// ---------------------------------------------------------------------------
__global__ __launch_bounds__(256) void proj_gemm_kernel(
    const short* __restrict__ a, const float* __restrict__ w,
    const float* __restrict__ pb, float* __restrict__ out) {
    __shared__ __align__(16) short lds_a[128 * 64];
    __shared__ __align__(16) short lds_b[128 * 64];
    const int tid  = threadIdx.x;
    const int lane = tid & 63;
    const int wv   = tid >> 6;
    const int wr   = wv >> 1, wc = wv & 1;
    const int bm   = blockIdx.y, bn = blockIdx.x;
    const int g    = lane >> 4, c16 = lane & 15;

    f32x4 acc[4][4] = {};
    const int arow = tid >> 3, ac8 = tid & 7;   // A: bf16, 8x16B chunks/row
    const int srow = tid >> 4, sc4 = tid & 15;  // B: fp32

    for (int kt = 0; kt < 12; ++kt) {
        #pragma unroll
        for (int r4 = 0; r4 < 4; ++r4) {
            int row = arow + r4 * 32;
            int gr  = bm * 128 + row; if (gr > M_TOK - 1) gr = M_TOK - 1;
            bf16x8 v = *(const bf16x8*)(a + (size_t)gr * DIMC + kt * 64 + ac8 * 8);
            *(bf16x8*)&lds_a[row * 64 + ((ac8 * 8) ^ ((row & 7) << 3))] = v;
        }
        #pragma unroll
        for (int r8 = 0; r8 < 8; ++r8) {
            int row = srow + r8 * 16;
            int gc  = bn * 128 + row;
            const float4 v = *(const float4*)(w + (size_t)gc * DIMC + kt * 64 + sc4 * 4);
            s16x4 bv; bv[0] = f2bf(v.x); bv[1] = f2bf(v.y); bv[2] = f2bf(v.z); bv[3] = f2bf(v.w);
            *(s16x4*)&lds_b[row * 64 + ((sc4 * 4) ^ ((row & 7) << 3))] = bv;
        }
        __syncthreads();
        #pragma unroll
        for (int ks = 0; ks < 2; ++ks) {
            bf16x8 af[4], bfr[4];
            const int kk = ks * 32 + (g << 3);
            #pragma unroll
            for (int i = 0; i < 4; ++i) {
                int row = wr * 64 + i * 16 + c16;
                af[i] = *(const bf16x8*)&lds_a[row * 64 + (kk ^ ((row & 7) << 3))];
            }
            #pragma unroll
            for (int j = 0; j < 4; ++j) {
                int row = wc * 64 + j * 16 + c16;
                bfr[j] = *(const bf16x8*)&lds_b[row * 64 + (kk ^ ((row & 7) << 3))];
            }
            #pragma unroll
            for (int i = 0; i < 4; ++i)
                #pragma unroll
                for (int j = 0; j < 4; ++j)
                    acc[i][j] = __builtin_amdgcn_mfma_f32_16x16x32_bf16(af[i], bfr[j], acc[i][j], 0, 0, 0);
        }
        __syncthreads();
    }

    #pragma unroll
    for (int i = 0; i < 4; ++i) {
        const int tbase = bm * 128 + wr * 64 + i * 16 + (g << 2);
        #pragma unroll
        for (int j = 0; j < 4; ++j) {
            const int c   = bn * 128 + wc * 64 + j * 16 + c16;
            const float bias = pb[c];
            #pragma unroll
            for (int rg = 0; rg < 4; ++rg) {
                const int tt = tbase + rg;
                if (tt >= M_TOK) continue;
                out[(size_t)tt * DIMC + c] = acc[i][j][rg] + bias;
            }
        }
    }
}

// ---------------------------------------------------------------------------
// Workspace layout (bytes):
//   q_ws  : 768*197*64   bf16 = 19,368,192
//   k_ws  : 768*197*64   bf16 = 19,368,192
//   vt_ws : 768*64*224   bf16 = 22,020,096  (m-padded; pads read only * P==0)
//   o_ws  : 12608*768    bf16 = 19,365,888
//   rpb   : 12*38809     f32  =  1,862,832     total ~82 MB
// ---------------------------------------------------------------------------
extern "C" void kernel_launch(void* const* d_in, const int* in_sizes, int n_in,
                              void* d_out, int out_size, void* d_ws, size_t ws_size,
                              hipStream_t stream) {
    const float* x       = (const float*)d_in[0];
    const float* qkv_w   = (const float*)d_in[1];
    const float* q_bias  = (const float*)d_in[2];
    const float* v_bias  = (const float*)d_in[3];
    const float* rpb_tab = (const float*)d_in[4];
    const float* proj_w  = (const float*)d_in[5];
    const float* proj_b  = (const float*)d_in[6];
    const int*   rel_idx = (const int*)d_in[7];
    float* out = (float*)d_out;

    char* ws = (char*)d_ws;
    short* q_ws    = (short*)(ws);
    short* k_ws    = (short*)(ws + 19368192);
    short* vt_ws   = (short*)(ws + 38736384);
    short* o_ws    = (short*)(ws + 60756480);
    float* rpb_full = (float*)(ws + 80122368);

    rpb_kernel<<<(NPAIR + 255) / 256, 256, 0, stream>>>(rpb_tab, rel_idx, rpb_full);
    qkv_gemm_kernel<<<dim3(18, 99), 256, 0, stream>>>(x, qkv_w, q_bias, v_bias,
                                                      q_ws, k_ws, vt_ws);
    attn_kernel<<<dim3(13, 768), 64, 0, stream>>>(q_ws, k_ws, vt_ws, rpb_full, o_ws);
    proj_gemm_kernel<<<dim3(6, 99), 256, 0, stream>>>(o_ws, proj_w, proj_b, out);
}

// Round 3
// 336.640 us; speedup vs baseline: 1.0282x; 1.0282x over previous
//
#include <hip/hip_runtime.h>
#include <hip/hip_bf16.h>

// Problem constants
#define HEADS   12
#define HD      64
#define NTOK    197          // N_PATCH + 1
#define BATCH   64
#define M_TOK   (BATCH*NTOK) // 12608
#define DIMC    768
#define NPAIR   (NTOK*NTOK)  // 38809
#define MPAD    224          // key/m dimension padded to 7*32

typedef __attribute__((ext_vector_type(8))) short bf16x8;  // 8 bf16 (4 VGPRs)
typedef __attribute__((ext_vector_type(4))) short s16x4;
typedef __attribute__((ext_vector_type(4))) float f32x4;

// fp32 -> bf16 round-to-nearest-even
static __device__ __forceinline__ short f2bf(float f) {
    unsigned u = __float_as_uint(f);
    unsigned r = (u + 0x7FFFu + ((u >> 16) & 1u)) >> 16;
    return (short)r;
}

// ---------------------------------------------------------------------------
// Kernel 0a: fp32 -> bf16 bulk convert (vectorized, n % 4 == 0)
// ---------------------------------------------------------------------------
__global__ void cvt_kernel(const float* __restrict__ src, short* __restrict__ dst, int n) {
    int i = (blockIdx.x * 256 + threadIdx.x) * 4;
    if (i >= n) return;
    const float4 v = *(const float4*)(src + i);
    s16x4 b; b[0] = f2bf(v.x); b[1] = f2bf(v.y); b[2] = f2bf(v.z); b[3] = f2bf(v.w);
    *(s16x4*)(dst + i) = b;
}

// ---------------------------------------------------------------------------
// Kernel 0b: expand rpb_table via rel_pos_index -> rpb_full[h][n*197+m]
// ---------------------------------------------------------------------------
__global__ void rpb_kernel(const float* __restrict__ table,
                           const int* __restrict__ idx,
                           float* __restrict__ rpb_full) {
    int i = blockIdx.x * 256 + threadIdx.x;
    if (i >= NPAIR) return;
    int id = idx[i];
    #pragma unroll
    for (int h = 0; h < HEADS; ++h)
        rpb_full[(size_t)h * NPAIR + i] = table[id * HEADS + h];
}

// ---------------------------------------------------------------------------
// Kernel 1: QKV GEMM (bf16 in, m97 structure: linear LDS + global_load_lds x16)
// 128x128 tile, BK=64, 4 waves of 64x64. Epilogue scatters q (scaled), k, v^T.
// ---------------------------------------------------------------------------
__global__ __launch_bounds__(256) void qkv_gemm_kernel(
    const short* __restrict__ xb, const short* __restrict__ wb,
    const float* __restrict__ qb, const float* __restrict__ vb,
    short* __restrict__ q_ws, short* __restrict__ k_ws,
    short* __restrict__ vt_ws) {
    __shared__ __align__(16) short lds_a[128 * 64];
    __shared__ __align__(16) short lds_b[128 * 64];
    const int tid  = threadIdx.x;
    const int lane = tid & 63;
    const int wv   = tid >> 6;           // 0..3
    const int wr   = wv >> 1, wc = wv & 1;
    const int bm   = blockIdx.y, bn = blockIdx.x;
    const int g    = lane >> 4, c16 = lane & 15;

    f32x4 acc[4][4] = {};

    // staging addresses: wave wv instr i covers LDS rows (wv*4+i)*8 .. +7;
    // lane l -> row +(l>>3), col shorts (l&7)*8 (16B). HW writes base + lane*16.
    const int lrow = lane >> 3;
    const int lcol = (lane & 7) * 8;
    const short* aptr[4];
    const short* bptr[4];
    #pragma unroll
    for (int i = 0; i < 4; ++i) {
        const int r  = (wv * 4 + i) * 8 + lrow;
        int gr = bm * 128 + r; if (gr > M_TOK - 1) gr = M_TOK - 1;
        aptr[i] = xb + (size_t)gr * DIMC + lcol;
        bptr[i] = wb + (size_t)(bn * 128 + r) * DIMC + lcol;
    }

    for (int kt = 0; kt < 12; ++kt) {
        #pragma unroll
        for (int i = 0; i < 4; ++i) {
            __builtin_amdgcn_global_load_lds(
                (const __attribute__((address_space(1))) void*)(aptr[i] + kt * 64),
                (__attribute__((address_space(3))) void*)&lds_a[(wv * 4 + i) * 512],
                16, 0, 0);
            __builtin_amdgcn_global_load_lds(
                (const __attribute__((address_space(1))) void*)(bptr[i] + kt * 64),
                (__attribute__((address_space(3))) void*)&lds_b[(wv * 4 + i) * 512],
                16, 0, 0);
        }
        __syncthreads();
        #pragma unroll
        for (int ks = 0; ks < 2; ++ks) {
            bf16x8 af[4], bfr[4];
            const int kk = ks * 32 + (g << 3);
            #pragma unroll
            for (int i = 0; i < 4; ++i)
                af[i] = *(const bf16x8*)&lds_a[(wr * 64 + i * 16 + c16) * 64 + kk];
            #pragma unroll
            for (int j = 0; j < 4; ++j)
                bfr[j] = *(const bf16x8*)&lds_b[(wc * 64 + j * 16 + c16) * 64 + kk];
            #pragma unroll
            for (int i = 0; i < 4; ++i)
                #pragma unroll
                for (int j = 0; j < 4; ++j)
                    acc[i][j] = __builtin_amdgcn_mfma_f32_16x16x32_bf16(af[i], bfr[j], acc[i][j], 0, 0, 0);
        }
        __syncthreads();
    }

    // epilogue: C/D layout col = lane&15, row = (lane>>4)*4 + reg  [m89-verified]
    #pragma unroll
    for (int i = 0; i < 4; ++i) {
        const int tbase = bm * 128 + wr * 64 + i * 16 + (g << 2);
        #pragma unroll
        for (int j = 0; j < 4; ++j) {
            const int c     = bn * 128 + wc * 64 + j * 16 + c16;
            const int which = c / DIMC;            // 0=q 1=k 2=v
            const int r     = c - which * DIMC;
            const int h     = r >> 6, d = r & 63;
            #pragma unroll
            for (int rg = 0; rg < 4; ++rg) {
                const int tt = tbase + rg;
                if (tt >= M_TOK) continue;
                const int b = tt / NTOK, n = tt - b * NTOK;
                const size_t bh = (size_t)b * HEADS + h;
                float val = acc[i][j][rg];
                if (which == 0) {
                    val = (val + qb[r]) * 0.125f;                    // q scale hd^-0.5
                    q_ws[(bh * NTOK + n) * HD + d] = f2bf(val);
                } else if (which == 1) {
                    k_ws[(bh * NTOK + n) * HD + d] = f2bf(val);
                } else {
                    val += vb[r];
                    vt_ws[(bh * HD + d) * MPAD + n] = f2bf(val);     // transposed for PV B-frags
                }
            }
        }
    }
}

// ---------------------------------------------------------------------------
// Kernel 2: attention. 1 wave per (b,h, 16-row tile). Q/K/V fragments read
// straight from global (L2-resident per (b,h)); only P staged in LDS.
// ---------------------------------------------------------------------------
__global__ __launch_bounds__(64) void attn_kernel(
    const short* __restrict__ q_ws, const short* __restrict__ k_ws,
    const short* __restrict__ vt_ws, const float* __restrict__ rpb_full,
    short* __restrict__ o_ws) {
    __shared__ __align__(16) short p_lds[16 * 232];   // rows padded to 232
    const int lane = threadIdx.x;
    const int rt   = blockIdx.x;                      // 0..12 row tile
    const int bh   = blockIdx.y;                      // 0..767
    const int b    = bh / HEADS, h = bh - b * HEADS;
    const int g    = lane >> 4, c16 = lane & 15;

    bf16x8 qa0, qa1;
    {
        const size_t base = ((size_t)bh * NTOK + (rt * 16 + c16)) * HD + g * 8;
        qa0 = *(const bf16x8*)(q_ws + base);
        qa1 = *(const bf16x8*)(q_ws + base + 32);
    }

    f32x4 sacc[14];
    #pragma unroll
    for (int t = 0; t < 14; ++t) sacc[t] = (f32x4){0.f, 0.f, 0.f, 0.f};
    #pragma unroll
    for (int mt = 0; mt < 14; ++mt) {
        const size_t base = ((size_t)bh * NTOK + (mt * 16 + c16)) * HD + g * 8;
        bf16x8 kb0 = *(const bf16x8*)(k_ws + base);
        bf16x8 kb1 = *(const bf16x8*)(k_ws + base + 32);
        sacc[mt] = __builtin_amdgcn_mfma_f32_16x16x32_bf16(qa0, kb0, sacc[mt], 0, 0, 0);
        sacc[mt] = __builtin_amdgcn_mfma_f32_16x16x32_bf16(qa1, kb1, sacc[mt], 0, 0, 0);
    }

    float mx[4] = {-1e30f, -1e30f, -1e30f, -1e30f};
    #pragma unroll
    for (int rg = 0; rg < 4; ++rg) {
        const int n = rt * 16 + g * 4 + rg;
        #pragma unroll
        for (int mt = 0; mt < 14; ++mt) {
            const int m = mt * 16 + c16;
            float s = sacc[mt][rg];
            if (n < NTOK && m < NTOK) s += rpb_full[(size_t)h * NPAIR + n * NTOK + m];
            else                      s = -1e30f;
            sacc[mt][rg] = s;
            mx[rg] = fmaxf(mx[rg], s);
        }
    }
    #pragma unroll
    for (int off = 1; off < 16; off <<= 1)
        #pragma unroll
        for (int rg = 0; rg < 4; ++rg)
            mx[rg] = fmaxf(mx[rg], __shfl_xor(mx[rg], off, 64));

    float sm[4] = {0.f, 0.f, 0.f, 0.f};
    #pragma unroll
    for (int mt = 0; mt < 14; ++mt)
        #pragma unroll
        for (int rg = 0; rg < 4; ++rg) {
            float p = exp2f((sacc[mt][rg] - mx[rg]) * 1.44269504f);
            sm[rg] += p;
            p_lds[(g * 4 + rg) * 232 + mt * 16 + c16] = f2bf(p);
        }
    #pragma unroll
    for (int off = 1; off < 16; off <<= 1)
        #pragma unroll
        for (int rg = 0; rg < 4; ++rg)
            sm[rg] += __shfl_xor(sm[rg], off, 64);
    __syncthreads();

    f32x4 oacc[4] = {};
    #pragma unroll
    for (int ks = 0; ks < 7; ++ks) {
        const int kk = ks * 32 + g * 8;
        bf16x8 pa = *(const bf16x8*)&p_lds[c16 * 232 + kk];
        #pragma unroll
        for (int j = 0; j < 4; ++j) {
            const int d = j * 16 + c16;
            bf16x8 vbf = *(const bf16x8*)(vt_ws + ((size_t)bh * HD + d) * MPAD + kk);
            oacc[j] = __builtin_amdgcn_mfma_f32_16x16x32_bf16(pa, vbf, oacc[j], 0, 0, 0);
        }
    }

    #pragma unroll
    for (int rg = 0; rg < 4; ++rg) {
        const int n = rt * 16 + g * 4 + rg;
        if (n >= NTOK) continue;
        const float inv = 1.0f / sm[rg];
        #pragma unroll
        for (int j = 0; j < 4; ++j)
            o_ws[((size_t)(b * NTOK + n)) * DIMC + h * HD + j * 16 + c16] =
                f2bf(oacc[j][rg] * inv);
    }
}

// ---------------------------------------------------------------------------
// Kernel 3: proj GEMM (o_ws bf16 @ pw_bf^T + proj_b) -> fp32 out; m97 structure
// ---------------------------------------------------------------------------
__global__ __launch_bounds__(256) void proj_gemm_kernel(
    const short* __restrict__ a, const short* __restrict__ wb,
    const float* __restrict__ pb, float* __restrict__ out) {
    __shared__ __align__(16) short lds_a[128 * 64];
    __shared__ __align__(16) short lds_b[128 * 64];
    const int tid  = threadIdx.x;
    const int lane = tid & 63;
    const int wv   = tid >> 6;
    const int wr   = wv >> 1, wc = wv & 1;
    const int bm   = blockIdx.y, bn = blockIdx.x;
    const int g    = lane >> 4, c16 = lane & 15;

    f32x4 acc[4][4] = {};

    const int lrow = lane >> 3;
    const int lcol = (lane & 7) * 8;
    const short* aptr[4];
    const short* bptr[4];
    #pragma unroll
    for (int i = 0; i < 4; ++i) {
        const int r  = (wv * 4 + i) * 8 + lrow;
        int gr = bm * 128 + r; if (gr > M_TOK - 1) gr = M_TOK - 1;
        aptr[i] = a  + (size_t)gr * DIMC + lcol;
        bptr[i] = wb + (size_t)(bn * 128 + r) * DIMC + lcol;
    }

    for (int kt = 0; kt < 12; ++kt) {
        #pragma unroll
        for (int i = 0; i < 4; ++i) {
            __builtin_amdgcn_global_load_lds(
                (const __attribute__((address_space(1))) void*)(aptr[i] + kt * 64),
                (__attribute__((address_space(3))) void*)&lds_a[(wv * 4 + i) * 512],
                16, 0, 0);
            __builtin_amdgcn_global_load_lds(
                (const __attribute__((address_space(1))) void*)(bptr[i] + kt * 64),
                (__attribute__((address_space(3))) void*)&lds_b[(wv * 4 + i) * 512],
                16, 0, 0);
        }
        __syncthreads();
        #pragma unroll
        for (int ks = 0; ks < 2; ++ks) {
            bf16x8 af[4], bfr[4];
            const int kk = ks * 32 + (g << 3);
            #pragma unroll
            for (int i = 0; i < 4; ++i)
                af[i] = *(const bf16x8*)&lds_a[(wr * 64 + i * 16 + c16) * 64 + kk];
            #pragma unroll
            for (int j = 0; j < 4; ++j)
                bfr[j] = *(const bf16x8*)&lds_b[(wc * 64 + j * 16 + c16) * 64 + kk];
            #pragma unroll
            for (int i = 0; i < 4; ++i)
                #pragma unroll
                for (int j = 0; j < 4; ++j)
                    acc[i][j] = __builtin_amdgcn_mfma_f32_16x16x32_bf16(af[i], bfr[j], acc[i][j], 0, 0, 0);
        }
        __syncthreads();
    }

    #pragma unroll
    for (int i = 0; i < 4; ++i) {
        const int tbase = bm * 128 + wr * 64 + i * 16 + (g << 2);
        #pragma unroll
        for (int j = 0; j < 4; ++j) {
            const int c   = bn * 128 + wc * 64 + j * 16 + c16;
            const float bias = pb[c];
            #pragma unroll
            for (int rg = 0; rg < 4; ++rg) {
                const int tt = tbase + rg;
                if (tt >= M_TOK) continue;
                out[(size_t)tt * DIMC + c] = acc[i][j][rg] + bias;
            }
        }
    }
}

// ---------------------------------------------------------------------------
// Workspace layout (bytes):
//   q_ws   : 19,368,192   @ 0
//   k_ws   : 19,368,192   @ 19,368,192
//   vt_ws  : 22,020,096   @ 38,736,384
//   x_bf / o_ws : 19,365,888 @ 60,756,480  (aliased: x_bf dead before attn)
//   rpb    :  1,862,832   @ 80,122,368
//   w_bf   :  3,538,944   @ 81,985,200
//   pw_bf  :  1,179,648   @ 85,524,144    total 86,703,792
// ---------------------------------------------------------------------------
extern "C" void kernel_launch(void* const* d_in, const int* in_sizes, int n_in,
                              void* d_out, int out_size, void* d_ws, size_t ws_size,
                              hipStream_t stream) {
    const float* x       = (const float*)d_in[0];
    const float* qkv_w   = (const float*)d_in[1];
    const float* q_bias  = (const float*)d_in[2];
    const float* v_bias  = (const float*)d_in[3];
    const float* rpb_tab = (const float*)d_in[4];
    const float* proj_w  = (const float*)d_in[5];
    const float* proj_b  = (const float*)d_in[6];
    const int*   rel_idx = (const int*)d_in[7];
    float* out = (float*)d_out;

    char* ws = (char*)d_ws;
    short* q_ws     = (short*)(ws);
    short* k_ws     = (short*)(ws + 19368192);
    short* vt_ws    = (short*)(ws + 38736384);
    short* x_bf     = (short*)(ws + 60756480);   // aliased with o_ws
    short* o_ws     = (short*)(ws + 60756480);
    float* rpb_full = (float*)(ws + 80122368);
    short* w_bf     = (short*)(ws + 81985200);
    short* pw_bf    = (short*)(ws + 85524144);

    const int nx = M_TOK * DIMC;          // 9,682,944
    const int nw = 3 * DIMC * DIMC;       // 1,769,472
    const int np = DIMC * DIMC;           //   589,824
    cvt_kernel<<<(nx / 4 + 255) / 256, 256, 0, stream>>>(x, x_bf, nx);
    cvt_kernel<<<(nw / 4 + 255) / 256, 256, 0, stream>>>(qkv_w, w_bf, nw);
    cvt_kernel<<<(np / 4 + 255) / 256, 256, 0, stream>>>(proj_w, pw_bf, np);
    rpb_kernel<<<(NPAIR + 255) / 256, 256, 0, stream>>>(rpb_tab, rel_idx, rpb_full);

    qkv_gemm_kernel<<<dim3(18, 99), 256, 0, stream>>>(x_bf, w_bf, q_bias, v_bias,
                                                      q_ws, k_ws, vt_ws);
    attn_kernel<<<dim3(13, 768), 64, 0, stream>>>(q_ws, k_ws, vt_ws, rpb_full, o_ws);
    proj_gemm_kernel<<<dim3(6, 99), 256, 0, stream>>>(o_ws, pw_bf, proj_b, out);
}

// Round 4
// 316.483 us; speedup vs baseline: 1.0937x; 1.0637x over previous
//
#include <hip/hip_runtime.h>
#include <hip/hip_bf16.h>

// Problem constants
#define HEADS   12
#define HD      64
#define NTOK    197          // N_PATCH + 1
#define BATCH   64
#define M_TOK   (BATCH*NTOK) // 12608
#define DIMC    768
#define NPAIR   (NTOK*NTOK)  // 38809
#define MPAD    224          // key/m dimension padded to 7*32

typedef __attribute__((ext_vector_type(8))) short bf16x8;  // 8 bf16 (4 VGPRs)
typedef __attribute__((ext_vector_type(4))) short s16x4;
typedef __attribute__((ext_vector_type(4))) float f32x4;

// fp32 -> bf16 round-to-nearest-even
static __device__ __forceinline__ short f2bf(float f) {
    unsigned u = __float_as_uint(f);
    unsigned r = (u + 0x7FFFu + ((u >> 16) & 1u)) >> 16;
    return (short)r;
}

// ---------------------------------------------------------------------------
// Kernel 0a: fused fp32 -> bf16 bulk convert of x, qkv_w, proj_w (one launch)
// ---------------------------------------------------------------------------
#define NX (M_TOK * DIMC)        // 9,682,944
#define NW (3 * DIMC * DIMC)     // 1,769,472
#define NP (DIMC * DIMC)         //   589,824
__global__ void cvt_kernel(const float* __restrict__ s0, short* __restrict__ d0,
                           const float* __restrict__ s1, short* __restrict__ d1,
                           const float* __restrict__ s2, short* __restrict__ d2) {
    int i = (blockIdx.x * 256 + threadIdx.x) * 4;
    const float* s; short* d;
    if (i < NX)                { s = s0 + i; d = d0 + i; }
    else if (i < NX + NW)      { s = s1 + (i - NX); d = d1 + (i - NX); }
    else if (i < NX + NW + NP) { s = s2 + (i - NX - NW); d = d2 + (i - NX - NW); }
    else return;
    const float4 v = *(const float4*)s;
    s16x4 b; b[0] = f2bf(v.x); b[1] = f2bf(v.y); b[2] = f2bf(v.z); b[3] = f2bf(v.w);
    *(s16x4*)d = b;
}

// ---------------------------------------------------------------------------
// Kernel 0b: expand rpb_table via rel_pos_index -> rpb_full[h][n*197+m]
// ---------------------------------------------------------------------------
__global__ void rpb_kernel(const float* __restrict__ table,
                           const int* __restrict__ idx,
                           float* __restrict__ rpb_full) {
    int i = blockIdx.x * 256 + threadIdx.x;
    if (i >= NPAIR) return;
    int id = idx[i];
    #pragma unroll
    for (int h = 0; h < HEADS; ++h)
        rpb_full[(size_t)h * NPAIR + i] = table[id * HEADS + h];
}

// ---------------------------------------------------------------------------
// Shared GEMM building blocks: 128x128 tile, BK=64, 4 waves of 64x64,
// 2-phase double-buffered staging (stage next tile BEFORE computing current;
// single __syncthreads per K-step AFTER compute so the barrier's vmcnt(0)
// drain overlaps the MFMA phase).  Four distinct LDS arrays -> static alias
// disambiguation (no conservative mid-loop waitcnt).
// ---------------------------------------------------------------------------
#define STAGE(LA, LB, kt)                                                       \
    _Pragma("unroll")                                                           \
    for (int i = 0; i < 4; ++i) {                                               \
        __builtin_amdgcn_global_load_lds(                                       \
            (const __attribute__((address_space(1))) void*)(aptr[i] + (kt) * 64),\
            (__attribute__((address_space(3))) void*)&LA[(wv * 4 + i) * 512],   \
            16, 0, 0);                                                          \
        __builtin_amdgcn_global_load_lds(                                       \
            (const __attribute__((address_space(1))) void*)(bptr[i] + (kt) * 64),\
            (__attribute__((address_space(3))) void*)&LB[(wv * 4 + i) * 512],   \
            16, 0, 0);                                                          \
    }

#define COMPUTE(LA, LB)                                                         \
    _Pragma("unroll")                                                           \
    for (int ks = 0; ks < 2; ++ks) {                                            \
        bf16x8 af[4], bfr[4];                                                   \
        const int kk = ks * 32 + (g << 3);                                      \
        _Pragma("unroll")                                                       \
        for (int i = 0; i < 4; ++i)                                             \
            af[i] = *(const bf16x8*)&LA[(wr * 64 + i * 16 + c16) * 64 + kk];    \
        _Pragma("unroll")                                                       \
        for (int j = 0; j < 4; ++j)                                             \
            bfr[j] = *(const bf16x8*)&LB[(wc * 64 + j * 16 + c16) * 64 + kk];   \
        _Pragma("unroll")                                                       \
        for (int i = 0; i < 4; ++i)                                             \
            _Pragma("unroll")                                                   \
            for (int j = 0; j < 4; ++j)                                         \
                acc[i][j] = __builtin_amdgcn_mfma_f32_16x16x32_bf16(            \
                    af[i], bfr[j], acc[i][j], 0, 0, 0);                         \
    }

// ---------------------------------------------------------------------------
// Kernel 1: QKV GEMM (bf16 in), epilogue scatters q (scaled), k, v^T.
// ---------------------------------------------------------------------------
__global__ __launch_bounds__(256) void qkv_gemm_kernel(
    const short* __restrict__ xb, const short* __restrict__ wb,
    const float* __restrict__ qb, const float* __restrict__ vb,
    short* __restrict__ q_ws, short* __restrict__ k_ws,
    short* __restrict__ vt_ws) {
    __shared__ __align__(16) short lds_a0[128 * 64];
    __shared__ __align__(16) short lds_a1[128 * 64];
    __shared__ __align__(16) short lds_b0[128 * 64];
    __shared__ __align__(16) short lds_b1[128 * 64];
    const int tid  = threadIdx.x;
    const int lane = tid & 63;
    const int wv   = tid >> 6;           // 0..3
    const int wr   = wv >> 1, wc = wv & 1;
    const int bm   = blockIdx.y, bn = blockIdx.x;
    const int g    = lane >> 4, c16 = lane & 15;

    f32x4 acc[4][4] = {};

    const int lrow = lane >> 3;
    const int lcol = (lane & 7) * 8;
    const short* aptr[4];
    const short* bptr[4];
    #pragma unroll
    for (int i = 0; i < 4; ++i) {
        const int r  = (wv * 4 + i) * 8 + lrow;
        int gr = bm * 128 + r; if (gr > M_TOK - 1) gr = M_TOK - 1;
        aptr[i] = xb + (size_t)gr * DIMC + lcol;
        bptr[i] = wb + (size_t)(bn * 128 + r) * DIMC + lcol;
    }

    STAGE(lds_a0, lds_b0, 0);
    __syncthreads();
    #pragma unroll
    for (int kp = 0; kp < 6; ++kp) {
        STAGE(lds_a1, lds_b1, 2 * kp + 1);
        COMPUTE(lds_a0, lds_b0);
        __syncthreads();
        if (kp < 5) { STAGE(lds_a0, lds_b0, 2 * kp + 2); }
        COMPUTE(lds_a1, lds_b1);
        if (kp < 5) __syncthreads();
    }

    // epilogue: C/D layout col = lane&15, row = (lane>>4)*4 + reg  [m89-verified]
    #pragma unroll
    for (int i = 0; i < 4; ++i) {
        const int tbase = bm * 128 + wr * 64 + i * 16 + (g << 2);
        #pragma unroll
        for (int j = 0; j < 4; ++j) {
            const int c     = bn * 128 + wc * 64 + j * 16 + c16;
            const int which = c / DIMC;            // 0=q 1=k 2=v
            const int r     = c - which * DIMC;
            const int h     = r >> 6, d = r & 63;
            #pragma unroll
            for (int rg = 0; rg < 4; ++rg) {
                const int tt = tbase + rg;
                if (tt >= M_TOK) continue;
                const int b = tt / NTOK, n = tt - b * NTOK;
                const size_t bh = (size_t)b * HEADS + h;
                float val = acc[i][j][rg];
                if (which == 0) {
                    val = (val + qb[r]) * 0.125f;                    // q scale hd^-0.5
                    q_ws[(bh * NTOK + n) * HD + d] = f2bf(val);
                } else if (which == 1) {
                    k_ws[(bh * NTOK + n) * HD + d] = f2bf(val);
                } else {
                    val += vb[r];
                    vt_ws[(bh * HD + d) * MPAD + n] = f2bf(val);     // transposed for PV B-frags
                }
            }
        }
    }
}

// ---------------------------------------------------------------------------
// Kernel 2: attention. 1 wave per (b,h, 16-row tile). Q/K/V fragments read
// straight from global (L2-resident per (b,h)); only P staged in LDS.
// ---------------------------------------------------------------------------
__global__ __launch_bounds__(64) void attn_kernel(
    const short* __restrict__ q_ws, const short* __restrict__ k_ws,
    const short* __restrict__ vt_ws, const float* __restrict__ rpb_full,
    short* __restrict__ o_ws) {
    __shared__ __align__(16) short p_lds[16 * 232];   // rows padded to 232
    const int lane = threadIdx.x;
    const int rt   = blockIdx.x;                      // 0..12 row tile
    const int bh   = blockIdx.y;                      // 0..767
    const int b    = bh / HEADS, h = bh - b * HEADS;
    const int g    = lane >> 4, c16 = lane & 15;

    bf16x8 qa0, qa1;
    {
        const size_t base = ((size_t)bh * NTOK + (rt * 16 + c16)) * HD + g * 8;
        qa0 = *(const bf16x8*)(q_ws + base);
        qa1 = *(const bf16x8*)(q_ws + base + 32);
    }

    f32x4 sacc[14];
    #pragma unroll
    for (int t = 0; t < 14; ++t) sacc[t] = (f32x4){0.f, 0.f, 0.f, 0.f};
    #pragma unroll
    for (int mt = 0; mt < 14; ++mt) {
        const size_t base = ((size_t)bh * NTOK + (mt * 16 + c16)) * HD + g * 8;
        bf16x8 kb0 = *(const bf16x8*)(k_ws + base);
        bf16x8 kb1 = *(const bf16x8*)(k_ws + base + 32);
        sacc[mt] = __builtin_amdgcn_mfma_f32_16x16x32_bf16(qa0, kb0, sacc[mt], 0, 0, 0);
        sacc[mt] = __builtin_amdgcn_mfma_f32_16x16x32_bf16(qa1, kb1, sacc[mt], 0, 0, 0);
    }

    float mx[4] = {-1e30f, -1e30f, -1e30f, -1e30f};
    #pragma unroll
    for (int rg = 0; rg < 4; ++rg) {
        const int n = rt * 16 + g * 4 + rg;
        #pragma unroll
        for (int mt = 0; mt < 14; ++mt) {
            const int m = mt * 16 + c16;
            float s = sacc[mt][rg];
            if (n < NTOK && m < NTOK) s += rpb_full[(size_t)h * NPAIR + n * NTOK + m];
            else                      s = -1e30f;
            sacc[mt][rg] = s;
            mx[rg] = fmaxf(mx[rg], s);
        }
    }
    #pragma unroll
    for (int off = 1; off < 16; off <<= 1)
        #pragma unroll
        for (int rg = 0; rg < 4; ++rg)
            mx[rg] = fmaxf(mx[rg], __shfl_xor(mx[rg], off, 64));

    float sm[4] = {0.f, 0.f, 0.f, 0.f};
    #pragma unroll
    for (int mt = 0; mt < 14; ++mt)
        #pragma unroll
        for (int rg = 0; rg < 4; ++rg) {
            float p = exp2f((sacc[mt][rg] - mx[rg]) * 1.44269504f);
            sm[rg] += p;
            p_lds[(g * 4 + rg) * 232 + mt * 16 + c16] = f2bf(p);
        }
    #pragma unroll
    for (int off = 1; off < 16; off <<= 1)
        #pragma unroll
        for (int rg = 0; rg < 4; ++rg)
            sm[rg] += __shfl_xor(sm[rg], off, 64);
    __syncthreads();

    f32x4 oacc[4] = {};
    #pragma unroll
    for (int ks = 0; ks < 7; ++ks) {
        const int kk = ks * 32 + g * 8;
        bf16x8 pa = *(const bf16x8*)&p_lds[c16 * 232 + kk];
        #pragma unroll
        for (int j = 0; j < 4; ++j) {
            const int d = j * 16 + c16;
            bf16x8 vbf = *(const bf16x8*)(vt_ws + ((size_t)bh * HD + d) * MPAD + kk);
            oacc[j] = __builtin_amdgcn_mfma_f32_16x16x32_bf16(pa, vbf, oacc[j], 0, 0, 0);
        }
    }

    #pragma unroll
    for (int rg = 0; rg < 4; ++rg) {
        const int n = rt * 16 + g * 4 + rg;
        if (n >= NTOK) continue;
        const float inv = 1.0f / sm[rg];
        #pragma unroll
        for (int j = 0; j < 4; ++j)
            o_ws[((size_t)(b * NTOK + n)) * DIMC + h * HD + j * 16 + c16] =
                f2bf(oacc[j][rg] * inv);
    }
}

// ---------------------------------------------------------------------------
// Kernel 3: proj GEMM (o_ws bf16 @ pw_bf^T + proj_b) -> fp32 out; 2-phase dbuf
// ---------------------------------------------------------------------------
__global__ __launch_bounds__(256) void proj_gemm_kernel(
    const short* __restrict__ a, const short* __restrict__ wb,
    const float* __restrict__ pb, float* __restrict__ out) {
    __shared__ __align__(16) short lds_a0[128 * 64];
    __shared__ __align__(16) short lds_a1[128 * 64];
    __shared__ __align__(16) short lds_b0[128 * 64];
    __shared__ __align__(16) short lds_b1[128 * 64];
    const int tid  = threadIdx.x;
    const int lane = tid & 63;
    const int wv   = tid >> 6;
    const int wr   = wv >> 1, wc = wv & 1;
    const int bm   = blockIdx.y, bn = blockIdx.x;
    const int g    = lane >> 4, c16 = lane & 15;

    f32x4 acc[4][4] = {};

    const int lrow = lane >> 3;
    const int lcol = (lane & 7) * 8;
    const short* aptr[4];
    const short* bptr[4];
    #pragma unroll
    for (int i = 0; i < 4; ++i) {
        const int r  = (wv * 4 + i) * 8 + lrow;
        int gr = bm * 128 + r; if (gr > M_TOK - 1) gr = M_TOK - 1;
        aptr[i] = a  + (size_t)gr * DIMC + lcol;
        bptr[i] = wb + (size_t)(bn * 128 + r) * DIMC + lcol;
    }

    STAGE(lds_a0, lds_b0, 0);
    __syncthreads();
    #pragma unroll
    for (int kp = 0; kp < 6; ++kp) {
        STAGE(lds_a1, lds_b1, 2 * kp + 1);
        COMPUTE(lds_a0, lds_b0);
        __syncthreads();
        if (kp < 5) { STAGE(lds_a0, lds_b0, 2 * kp + 2); }
        COMPUTE(lds_a1, lds_b1);
        if (kp < 5) __syncthreads();
    }

    #pragma unroll
    for (int i = 0; i < 4; ++i) {
        const int tbase = bm * 128 + wr * 64 + i * 16 + (g << 2);
        #pragma unroll
        for (int j = 0; j < 4; ++j) {
            const int c   = bn * 128 + wc * 64 + j * 16 + c16;
            const float bias = pb[c];
            #pragma unroll
            for (int rg = 0; rg < 4; ++rg) {
                const int tt = tbase + rg;
                if (tt >= M_TOK) continue;
                out[(size_t)tt * DIMC + c] = acc[i][j][rg] + bias;
            }
        }
    }
}

// ---------------------------------------------------------------------------
// Workspace layout (bytes):
//   q_ws   : 19,368,192   @ 0
//   k_ws   : 19,368,192   @ 19,368,192
//   vt_ws  : 22,020,096   @ 38,736,384
//   x_bf / o_ws : 19,365,888 @ 60,756,480  (aliased: x_bf dead before attn)
//   rpb    :  1,862,832   @ 80,122,368
//   w_bf   :  3,538,944   @ 81,985,200
//   pw_bf  :  1,179,648   @ 85,524,144    total 86,703,792
// ---------------------------------------------------------------------------
extern "C" void kernel_launch(void* const* d_in, const int* in_sizes, int n_in,
                              void* d_out, int out_size, void* d_ws, size_t ws_size,
                              hipStream_t stream) {
    const float* x       = (const float*)d_in[0];
    const float* qkv_w   = (const float*)d_in[1];
    const float* q_bias  = (const float*)d_in[2];
    const float* v_bias  = (const float*)d_in[3];
    const float* rpb_tab = (const float*)d_in[4];
    const float* proj_w  = (const float*)d_in[5];
    const float* proj_b  = (const float*)d_in[6];
    const int*   rel_idx = (const int*)d_in[7];
    float* out = (float*)d_out;

    char* ws = (char*)d_ws;
    short* q_ws     = (short*)(ws);
    short* k_ws     = (short*)(ws + 19368192);
    short* vt_ws    = (short*)(ws + 38736384);
    short* x_bf     = (short*)(ws + 60756480);   // aliased with o_ws
    short* o_ws     = (short*)(ws + 60756480);
    float* rpb_full = (float*)(ws + 80122368);
    short* w_bf     = (short*)(ws + 81985200);
    short* pw_bf    = (short*)(ws + 85524144);

    const int ncvt = (NX + NW + NP) / 4;  // 3,010,560 float4 elements
    cvt_kernel<<<(ncvt + 255) / 256, 256, 0, stream>>>(x, x_bf, qkv_w, w_bf, proj_w, pw_bf);
    rpb_kernel<<<(NPAIR + 255) / 256, 256, 0, stream>>>(rpb_tab, rel_idx, rpb_full);

    qkv_gemm_kernel<<<dim3(18, 99), 256, 0, stream>>>(x_bf, w_bf, q_bias, v_bias,
                                                      q_ws, k_ws, vt_ws);
    attn_kernel<<<dim3(13, 768), 64, 0, stream>>>(q_ws, k_ws, vt_ws, rpb_full, o_ws);
    proj_gemm_kernel<<<dim3(6, 99), 256, 0, stream>>>(o_ws, pw_bf, proj_b, out);
}